// Round 1
// baseline (56.174 us; speedup 1.0000x reference)
//
#include <hip/hip_runtime.h>

#define K_TERMS 32   // series terms; ||B||inf * w_max <= ~5.1 -> tail < 1e-10 rel

// ws layout:
//   floats [0 .. K_TERMS-1] : coef_k = (alpha^T B^k s) / k!
//   float  [K_TERMS]        : c  (spectral shift)
//   byte offset 256         : double accumulator

__global__ void pt_setup_kernel(const float* __restrict__ S,
                                const float* __restrict__ alpha,
                                float* __restrict__ coef_c,
                                double* __restrict__ acc) {
    if (threadIdx.x != 0 || blockIdx.x != 0) return;
    double Sd[8][8], a[8], s[8];
    for (int i = 0; i < 8; ++i) {
        a[i] = (double)alpha[i];
        for (int j = 0; j < 8; ++j) Sd[i][j] = (double)S[i * 8 + j];
    }
    double c = 0.0;
    for (int i = 0; i < 8; ++i) {
        double rs = 0.0;
        for (int j = 0; j < 8; ++j) rs += Sd[i][j];
        s[i] = -rs;                       // exit vector (positive)
        double d = -Sd[i][i];
        if (d > c) c = d;
    }
    double B[8][8];
    for (int i = 0; i < 8; ++i)
        for (int j = 0; j < 8; ++j)
            B[i][j] = Sd[i][j] + (i == j ? c : 0.0);   // entrywise >= 0

    double v[8];
    for (int i = 0; i < 8; ++i) v[i] = s[i];
    for (int k = 0; k < K_TERMS; ++k) {
        if (k > 0) {
            double nv[8];
            double inv_k = 1.0 / (double)k;
            for (int i = 0; i < 8; ++i) {
                double m = 0.0;
                for (int j = 0; j < 8; ++j) m += B[i][j] * v[j];
                nv[i] = m * inv_k;        // fold 1/k! into iteration
            }
            for (int i = 0; i < 8; ++i) v[i] = nv[i];
        }
        double d = 0.0;
        for (int i = 0; i < 8; ++i) d += a[i] * v[i];
        coef_c[k] = (float)d;             // all coefficients >= 0
    }
    coef_c[K_TERMS] = (float)c;
    *acc = 0.0;                           // zero the accumulator every call
}

__device__ __forceinline__ float pt_logdens(float x, const float* coef, float c) {
    float p = coef[K_TERMS - 1];
#pragma unroll
    for (int k = K_TERMS - 2; k >= 0; --k) p = fmaf(p, x, coef[k]);
    // p > 0 always (positive coefficients, x > 0)
    return __logf(p) - c * x;
}

__global__ __launch_bounds__(256) void pt_score_kernel(const float* __restrict__ w,
                                                       int n,
                                                       const float* __restrict__ coef_c,
                                                       double* __restrict__ acc) {
    // uniform constants -> compiler emits scalar loads into SGPRs
    float coef[K_TERMS];
#pragma unroll
    for (int k = 0; k < K_TERMS; ++k) coef[k] = coef_c[k];
    const float c = coef_c[K_TERMS];

    double local = 0.0;
    const int tid = blockIdx.x * blockDim.x + threadIdx.x;
    const int nthreads = gridDim.x * blockDim.x;
    const int n4 = n >> 2;
    const float4* w4 = (const float4*)w;
    for (int i = tid; i < n4; i += nthreads) {
        float4 wv = w4[i];
        float acc4 = pt_logdens(wv.x, coef, c);
        acc4 += pt_logdens(wv.y, coef, c);
        acc4 += pt_logdens(wv.z, coef, c);
        acc4 += pt_logdens(wv.w, coef, c);
        local += (double)acc4;
    }
    for (int i = (n4 << 2) + tid; i < n; i += nthreads) {  // tail (n % 4)
        local += (double)pt_logdens(w[i], coef, c);
    }

    // wave(64) reduce
#pragma unroll
    for (int off = 32; off > 0; off >>= 1)
        local += __shfl_down(local, off, 64);

    __shared__ double red[4];  // 256 threads / 64
    const int wid = threadIdx.x >> 6;
    const int lane = threadIdx.x & 63;
    if (lane == 0) red[wid] = local;
    __syncthreads();
    if (threadIdx.x == 0) {
        double b = red[0] + red[1] + red[2] + red[3];
        atomicAdd(acc, b);                // global_atomic_add_f64 on gfx950
    }
}

__global__ void pt_write_kernel(const double* __restrict__ acc,
                                float* __restrict__ out) {
    if (threadIdx.x == 0 && blockIdx.x == 0) out[0] = (float)(*acc);
}

extern "C" void kernel_launch(void* const* d_in, const int* in_sizes, int n_in,
                              void* d_out, int out_size, void* d_ws, size_t ws_size,
                              hipStream_t stream) {
    const float* w     = (const float*)d_in[0];   // [N_W]
    const float* S     = (const float*)d_in[1];   // [8,8]
    const float* alpha = (const float*)d_in[2];   // [8]
    float* out = (float*)d_out;

    float*  coef_c = (float*)d_ws;
    double* acc    = (double*)((char*)d_ws + 256);

    const int n = in_sizes[0];

    pt_setup_kernel<<<1, 64, 0, stream>>>(S, alpha, coef_c, acc);

    int n4 = n >> 2;
    int blocks = (n4 + 255) / 256;
    if (blocks < 1) blocks = 1;
    if (blocks > 2048) blocks = 2048;
    pt_score_kernel<<<blocks, 256, 0, stream>>>(w, n, coef_c, acc);

    pt_write_kernel<<<1, 64, 0, stream>>>(acc, out);
}

// Round 2
// 15.256 us; speedup vs baseline: 3.6821x; 3.6821x over previous
//
#include <hip/hip_runtime.h>

#define K_TERMS 32   // ||B||inf * w_max <= ~6.6 -> 6.6^32/32! ~ 7e-10 rel tail

// Fused kernel: every block redundantly computes the 32 series coefficients
// d_k = (alpha^T B^k s)/k! (B = S + cI, entrywise >= 0 so zero cancellation,
// fp32 is fine) lane-parallel in wave 0, then scores its slice of w and
// writes one double partial per block. A tiny second kernel reduces partials.

__device__ __forceinline__ float pt_logdens(float x, const float* coef, float c) {
    float p = coef[K_TERMS - 1];
#pragma unroll
    for (int k = K_TERMS - 2; k >= 0; --k) p = fmaf(p, x, coef[k]);
    return __logf(p) - c * x;   // p > 0 always: nonneg coefs, x > 0
}

__global__ __launch_bounds__(256) void pt_fused_kernel(
    const float* __restrict__ w, int n,
    const float* __restrict__ S, const float* __restrict__ alpha,
    double* __restrict__ partials)
{
    __shared__ float s_coef[K_TERMS];
    __shared__ float s_c;

    // ---- lane-parallel coefficient computation (wave 0; lanes 0..7 active) ----
    if (threadIdx.x < 64) {
        const int lane = threadIdx.x;
        const bool act = lane < 8;
        const float a_i = act ? alpha[lane] : 0.0f;

        float Srow[8];
        float diag = 0.0f, rs = 0.0f;
#pragma unroll
        for (int j = 0; j < 8; ++j) {
            float sv = act ? S[lane * 8 + j] : 0.0f;
            Srow[j] = sv;
            rs += sv;
            diag = (j == lane) ? sv : diag;   // select, no dynamic reg index
        }
        // c = max_i(-S_ii), reduced over the 8-lane group
        float m = -diag;
        m = fmaxf(m, __shfl_xor(m, 1, 8));
        m = fmaxf(m, __shfl_xor(m, 2, 8));
        m = fmaxf(m, __shfl_xor(m, 4, 8));
        const float c = m;

        float Brow[8];
#pragma unroll
        for (int j = 0; j < 8; ++j)
            Brow[j] = Srow[j] + ((j == lane) ? c : 0.0f);   // B >= 0 entrywise

        float v = -rs;   // s_i = -sum_j S_ij  (> 0)

        {   // k = 0: d_0 = alpha . s
            float d = a_i * v;
            d += __shfl_xor(d, 1, 8);
            d += __shfl_xor(d, 2, 8);
            d += __shfl_xor(d, 4, 8);
            if (lane == 0) s_coef[0] = d;
        }
#pragma unroll
        for (int k = 1; k < K_TERMS; ++k) {
            // v <- (B v) / k ; 8 independent shuffles then an FMA chain
            float vj[8];
#pragma unroll
            for (int j = 0; j < 8; ++j) vj[j] = __shfl(v, j, 8);
            float mm = 0.0f;
#pragma unroll
            for (int j = 0; j < 8; ++j) mm = fmaf(Brow[j], vj[j], mm);
            v = mm * (1.0f / (float)k);       // constant after unroll

            float d = a_i * v;
            d += __shfl_xor(d, 1, 8);
            d += __shfl_xor(d, 2, 8);
            d += __shfl_xor(d, 4, 8);
            if (lane == 0) s_coef[k] = d;
        }
        if (lane == 0) s_c = c;
    }
    __syncthreads();

    // ---- score slice ----
    float coef[K_TERMS];
#pragma unroll
    for (int k = 0; k < K_TERMS; ++k) coef[k] = s_coef[k];
    const float c = s_c;

    double local = 0.0;
    const int tid = blockIdx.x * blockDim.x + threadIdx.x;
    const int nthreads = gridDim.x * blockDim.x;
    const int n4 = n >> 2;
    const float4* w4 = (const float4*)w;
    for (int i = tid; i < n4; i += nthreads) {
        float4 wv = w4[i];
        float a4 = pt_logdens(wv.x, coef, c);
        a4 += pt_logdens(wv.y, coef, c);
        a4 += pt_logdens(wv.z, coef, c);
        a4 += pt_logdens(wv.w, coef, c);
        local += (double)a4;
    }
    for (int i = (n4 << 2) + tid; i < n; i += nthreads)   // n % 4 tail
        local += (double)pt_logdens(w[i], coef, c);

    // ---- block reduce -> one double partial per block ----
#pragma unroll
    for (int off = 32; off > 0; off >>= 1)
        local += __shfl_down(local, off, 64);

    __shared__ double red[4];
    const int wid = threadIdx.x >> 6;
    const int lane = threadIdx.x & 63;
    if (lane == 0) red[wid] = local;
    __syncthreads();
    if (threadIdx.x == 0)
        partials[blockIdx.x] = red[0] + red[1] + red[2] + red[3];
}

__global__ __launch_bounds__(512) void pt_reduce_kernel(
    const double* __restrict__ partials, int nparts, float* __restrict__ out)
{
    double local = 0.0;
    for (int i = threadIdx.x; i < nparts; i += 512) local += partials[i];
#pragma unroll
    for (int off = 32; off > 0; off >>= 1)
        local += __shfl_down(local, off, 64);

    __shared__ double red[8];
    const int wid = threadIdx.x >> 6;
    const int lane = threadIdx.x & 63;
    if (lane == 0) red[wid] = local;
    __syncthreads();
    if (threadIdx.x == 0) {
        double t = 0.0;
#pragma unroll
        for (int i = 0; i < 8; ++i) t += red[i];
        out[0] = (float)t;
    }
}

extern "C" void kernel_launch(void* const* d_in, const int* in_sizes, int n_in,
                              void* d_out, int out_size, void* d_ws, size_t ws_size,
                              hipStream_t stream) {
    const float* w     = (const float*)d_in[0];   // [N_W]
    const float* S     = (const float*)d_in[1];   // [8,8]
    const float* alpha = (const float*)d_in[2];   // [8]
    float* out = (float*)d_out;

    double* partials = (double*)d_ws;

    const int n = in_sizes[0];
    int n4 = n >> 2;
    int blocks = (n4 + 255) / 256;
    if (blocks < 1) blocks = 1;
    if (blocks > 2048) blocks = 2048;     // grid-stride handles the rest

    pt_fused_kernel<<<blocks, 256, 0, stream>>>(w, n, S, alpha, partials);
    pt_reduce_kernel<<<1, 512, 0, stream>>>(partials, blocks, out);
}